// Round 1
// baseline (5974.949 us; speedup 1.0000x reference)
//
#include <hip/hip_runtime.h>

#define NB 2
#define CCH 64
#define LL 8
#define HH 160
#define WW 160
#define PP 8
#define NPH 20
#define NPW 20
#define NPAT (NB*NPH*NPW)      // 800
#define NE 8
#define HWX (HH*WW)            // 25600
#define CSTRIDE (LL*HWX)       // 204800

// ---------------- Router: pooled mean -> logits -> top-2 softmax ----------------
__global__ __launch_bounds__(256)
void router_kernel(const float* __restrict__ x,
                   const float* __restrict__ rw,
                   const float* __restrict__ rb,
                   int* __restrict__ sel_idx,
                   float* __restrict__ sel_w)
{
    int n = blockIdx.x;
    int b = n / (NPH*NPW);
    int rem = n - b*(NPH*NPW);
    int ph = rem / NPW, pw = rem - ph*NPW;
    int t = threadIdx.x;
    int c = t >> 2, part = t & 3;

    const float* xl0 = x + ((size_t)(b*CCH + c)*LL)*HWX + (size_t)(ph*PP)*WW + pw*PP;
    float s = 0.f;
    for (int l = part*2; l < part*2 + 2; ++l) {
        const float* xl = xl0 + (size_t)l*HWX;
        #pragma unroll
        for (int i = 0; i < 8; ++i) {
            float4 v0 = *(const float4*)(xl + i*WW);
            float4 v1 = *(const float4*)(xl + i*WW + 4);
            s += v0.x+v0.y+v0.z+v0.w + v1.x+v1.y+v1.z+v1.w;
        }
    }
    s += __shfl_xor(s, 1);
    s += __shfl_xor(s, 2);

    __shared__ float meanc[CCH];
    __shared__ float logits[NE];
    if (part == 0) meanc[c] = s * (1.f/512.f);
    __syncthreads();
    if (t < NE) {
        float acc = rb[t];
        for (int cc = 0; cc < CCH; ++cc) acc += meanc[cc] * rw[t*CCH + cc];
        logits[t] = acc;
    }
    __syncthreads();
    if (t == 0) {
        float m0 = -1e30f; int i0 = 0;
        #pragma unroll
        for (int e = 0; e < NE; ++e) { float v = logits[e]; if (v > m0) { m0 = v; i0 = e; } }
        float m1 = -1e30f; int i1 = 0;
        #pragma unroll
        for (int e = 0; e < NE; ++e) { if (e != i0) { float v = logits[e]; if (v > m1) { m1 = v; i1 = e; } } }
        float dd = __expf(m1 - m0);         // m0 >= m1
        float inv = 1.f / (1.f + dd);
        sel_idx[n*2]   = i0;  sel_idx[n*2+1] = i1;
        sel_w[n*2]     = inv; sel_w[n*2+1]   = dd * inv;
    }
}

// ---------------- Expert compute: one block per (patch, l) ----------------
// LDS: xin[64][64] | ybuf[64][64] | wstage[4096] = 48 KiB -> 3 blocks/CU
// wave q owns channels [16q,16q+16) at spatial s = lane
__global__ __launch_bounds__(256)
void moe_kernel(const float* __restrict__ x,
                const float* __restrict__ dw_w,
                const float* __restrict__ dw_b,
                const float* __restrict__ ln_g,
                const float* __restrict__ ln_b,
                const float* __restrict__ pwin_w,
                const float* __restrict__ pwin_b,
                const float* __restrict__ pwout_w,
                const float* __restrict__ pwout_b,
                const int* __restrict__ sel_idx,
                const float* __restrict__ sel_w,
                float* __restrict__ out)
{
    extern __shared__ float lds[];
    float* xin    = lds;          // 4096 f
    float* ybuf   = lds + 4096;   // 4096 f
    float* wstage = lds + 8192;   // 4096 f

    int bid = blockIdx.x;
    int n = bid >> 3;             // patch
    int l = bid & 7;              // time step
    int b = n / (NPH*NPW);
    int rem = n - b*(NPH*NPW);
    int ph = rem / NPW, pw = rem - ph*NPW;

    int t = threadIdx.x;
    int s = t & 63;               // spatial position (i0*8+j0)
    int q = t >> 6;               // wave id
    int i0 = s >> 3, j0 = s & 7;
    int cbase = q * 16;

    // ---- load input patch (vectorized) ----
    size_t xbl = ((size_t)(b*CCH)*LL + l)*HWX + (size_t)(ph*PP)*WW + pw*PP;
    for (int idx4 = t; idx4 < 1024; idx4 += 256) {
        int c = idx4 >> 4, r = idx4 & 15, i = r >> 1, j = (r & 1)*4;
        float4 v = *(const float4*)(x + xbl + (size_t)c*CSTRIDE + i*WW + j);
        *(float4*)(xin + c*64 + i*8 + j) = v;
    }

    int e0 = sel_idx[n*2], e1 = sel_idx[n*2+1];
    float w0 = sel_w[n*2],  w1 = sel_w[n*2+1];

    float out_acc[16];
    #pragma unroll
    for (int k = 0; k < 16; ++k) out_acc[k] = 0.f;

    for (int pass = 0; pass < 2; ++pass) {
        int e = pass ? e1 : e0;
        float we = pass ? w1 : w0;

        __syncthreads();   // xin ready (pass0) / prev pass reads of ybuf,wstage done (pass1)
        for (int idx = t; idx < CCH*49; idx += 256) wstage[idx] = dw_w[e*CCH*49 + idx];
        float lngv = ln_g[e*64 + s];
        float lnbv = ln_b[e*64 + s];
        __syncthreads();

        // ---- depthwise 7x7 (zero-padded within patch) + LayerNorm over 64 spatial ----
        #pragma unroll
        for (int k = 0; k < 16; ++k) {
            int c = cbase + k;
            const float* xr = xin + c*64;
            const float* wr = wstage + c*49;
            float acc = dw_b[e*CCH + c];
            #pragma unroll
            for (int di = 0; di < 7; ++di) {
                int i2 = i0 + di - 3;
                if ((unsigned)i2 < 8u) {
                    #pragma unroll
                    for (int dj = 0; dj < 7; ++dj) {
                        int j2 = j0 + dj - 3;
                        if ((unsigned)j2 < 8u) {
                            acc = fmaf(xr[i2*8 + j2], wr[di*7 + dj], acc);
                        }
                    }
                }
            }
            // wave-wide LN reduction (all 64 lanes = all spatial of this channel)
            float ssum = acc, ssq = acc*acc;
            #pragma unroll
            for (int m = 1; m < 64; m <<= 1) {
                ssum += __shfl_xor(ssum, m);
                ssq  += __shfl_xor(ssq, m);
            }
            float mu  = ssum * (1.f/64.f);
            float var = ssq * (1.f/64.f) - mu*mu;
            float inv = rsqrtf(var + 1e-5f);
            ybuf[c*64 + s] = (acc - mu) * inv * lngv + lnbv;
        }
        __syncthreads();

        // ---- stage pwin a-rows; preload y column into regs ----
        for (int idx = t; idx < 4096; idx += 256) wstage[idx] = pwin_w[e*8192 + idx];
        float yreg[64];
        #pragma unroll
        for (int c = 0; c < 64; ++c) yreg[c] = ybuf[c*64 + s];
        __syncthreads();

        float ha[16], hg[16];
        #pragma unroll
        for (int k = 0; k < 16; ++k) {
            const float* wa = wstage + (cbase + k)*64;
            float acc = pwin_b[e*128 + cbase + k];
            #pragma unroll
            for (int c4 = 0; c4 < 16; ++c4) {
                float4 v = *(const float4*)(wa + c4*4);
                acc = fmaf(yreg[c4*4+0], v.x, acc);
                acc = fmaf(yreg[c4*4+1], v.y, acc);
                acc = fmaf(yreg[c4*4+2], v.z, acc);
                acc = fmaf(yreg[c4*4+3], v.w, acc);
            }
            ha[k] = acc;
        }
        __syncthreads();
        for (int idx = t; idx < 4096; idx += 256) wstage[idx] = pwin_w[e*8192 + 4096 + idx];
        __syncthreads();
        #pragma unroll
        for (int k = 0; k < 16; ++k) {
            const float* wg = wstage + (cbase + k)*64;
            float acc = pwin_b[e*128 + 64 + cbase + k];
            #pragma unroll
            for (int c4 = 0; c4 < 16; ++c4) {
                float4 v = *(const float4*)(wg + c4*4);
                acc = fmaf(yreg[c4*4+0], v.x, acc);
                acc = fmaf(yreg[c4*4+1], v.y, acc);
                acc = fmaf(yreg[c4*4+2], v.z, acc);
                acc = fmaf(yreg[c4*4+3], v.w, acc);
            }
            hg[k] = acc;
        }

        // ---- SiLU gate ----
        float gated[16];
        #pragma unroll
        for (int k = 0; k < 16; ++k) {
            float a = ha[k];
            float sg = 1.f / (1.f + __expf(-a));
            gated[k] = a * sg * hg[k];
        }
        __syncthreads();   // all wstage (pwin-g) reads done
        #pragma unroll
        for (int k = 0; k < 16; ++k) ybuf[(cbase+k)*64 + s] = gated[k];
        for (int idx = t; idx < 4096; idx += 256) wstage[idx] = pwout_w[e*4096 + idx];
        __syncthreads();

        // ---- pw_out + residual + combine ----
        float greg[64];
        #pragma unroll
        for (int c = 0; c < 64; ++c) greg[c] = ybuf[c*64 + s];
        #pragma unroll
        for (int k = 0; k < 16; ++k) {
            const float* wo = wstage + (cbase + k)*64;
            float acc = pwout_b[e*64 + cbase + k];
            #pragma unroll
            for (int c4 = 0; c4 < 16; ++c4) {
                float4 v = *(const float4*)(wo + c4*4);
                acc = fmaf(greg[c4*4+0], v.x, acc);
                acc = fmaf(greg[c4*4+1], v.y, acc);
                acc = fmaf(greg[c4*4+2], v.z, acc);
                acc = fmaf(greg[c4*4+3], v.w, acc);
            }
            out_acc[k] = fmaf(we, xin[(cbase+k)*64 + s] + acc, out_acc[k]);
        }
    }

    // ---- write output ----
    size_t obl = ((size_t)(b*CCH)*LL + l)*HWX + (size_t)(ph*PP + i0)*WW + pw*PP + j0;
    #pragma unroll
    for (int k = 0; k < 16; ++k) {
        out[obl + (size_t)(cbase + k)*CSTRIDE] = out_acc[k];
    }
}

extern "C" void kernel_launch(void* const* d_in, const int* in_sizes, int n_in,
                              void* d_out, int out_size, void* d_ws, size_t ws_size,
                              hipStream_t stream) {
    const float* x        = (const float*)d_in[0];
    const float* router_w = (const float*)d_in[1];
    const float* router_b = (const float*)d_in[2];
    const float* dw_w     = (const float*)d_in[3];
    const float* dw_b     = (const float*)d_in[4];
    const float* ln_g     = (const float*)d_in[5];
    const float* ln_b     = (const float*)d_in[6];
    const float* pwin_w   = (const float*)d_in[7];
    const float* pwin_b   = (const float*)d_in[8];
    const float* pwout_w  = (const float*)d_in[9];
    const float* pwout_b  = (const float*)d_in[10];
    float* out = (float*)d_out;

    int*   sel_idx = (int*)d_ws;
    float* sel_w   = (float*)((char*)d_ws + NPAT*2*sizeof(int));

    router_kernel<<<NPAT, 256, 0, stream>>>(x, router_w, router_b, sel_idx, sel_w);
    moe_kernel<<<NPAT*LL, 256, 48*1024, stream>>>(x, dw_w, dw_b, ln_g, ln_b,
                                                  pwin_w, pwin_b, pwout_w, pwout_b,
                                                  sel_idx, sel_w, out);
}

// Round 2
// 4993.889 us; speedup vs baseline: 1.1965x; 1.1965x over previous
//
#include <hip/hip_runtime.h>

#define NB 2
#define CCH 64
#define LL 8
#define HH 160
#define WW 160
#define PP 8
#define NPH 20
#define NPW 20
#define NPAT (NB*NPH*NPW)      // 800
#define NE 8
#define HWX (HH*WW)            // 25600
#define CSTRIDE (LL*HWX)       // 204800

// ---------------- Router: pooled mean -> logits -> top-2 softmax ----------------
__global__ __launch_bounds__(256)
void router_kernel(const float* __restrict__ x,
                   const float* __restrict__ rw,
                   const float* __restrict__ rb,
                   int* __restrict__ sel_idx,
                   float* __restrict__ sel_w)
{
    int n = blockIdx.x;
    int b = n / (NPH*NPW);
    int rem = n - b*(NPH*NPW);
    int ph = rem / NPW, pw = rem - ph*NPW;
    int t = threadIdx.x;
    int c = t >> 2, part = t & 3;

    const float* xl0 = x + ((size_t)(b*CCH + c)*LL)*HWX + (size_t)(ph*PP)*WW + pw*PP;
    float s = 0.f;
    for (int l = part*2; l < part*2 + 2; ++l) {
        const float* xl = xl0 + (size_t)l*HWX;
        #pragma unroll
        for (int i = 0; i < 8; ++i) {
            float4 v0 = *(const float4*)(xl + i*WW);
            float4 v1 = *(const float4*)(xl + i*WW + 4);
            s += v0.x+v0.y+v0.z+v0.w + v1.x+v1.y+v1.z+v1.w;
        }
    }
    s += __shfl_xor(s, 1);
    s += __shfl_xor(s, 2);

    __shared__ float meanc[CCH];
    __shared__ float logits[NE];
    if (part == 0) meanc[c] = s * (1.f/512.f);
    __syncthreads();
    if (t < NE) {
        float acc = rb[t];
        for (int cc = 0; cc < CCH; ++cc) acc += meanc[cc] * rw[t*CCH + cc];
        logits[t] = acc;
    }
    __syncthreads();
    if (t == 0) {
        float m0 = -1e30f; int i0 = 0;
        #pragma unroll
        for (int e = 0; e < NE; ++e) { float v = logits[e]; if (v > m0) { m0 = v; i0 = e; } }
        float m1 = -1e30f; int i1 = 0;
        #pragma unroll
        for (int e = 0; e < NE; ++e) { if (e != i0) { float v = logits[e]; if (v > m1) { m1 = v; i1 = e; } } }
        float dd = __expf(m1 - m0);         // m0 >= m1
        float inv = 1.f / (1.f + dd);
        sel_idx[n*2]   = i0;  sel_idx[n*2+1] = i1;
        sel_w[n*2]     = inv; sel_w[n*2+1]   = dd * inv;
    }
}

// ---------------- Expert compute: one block per (patch, l) ----------------
// LDS: xin[64][64] + ybuf[64][64] = 32 KiB.
// Weights read via wave-uniform (SGPR) addresses -> scalar loads, L2-hot.
// wave q owns channels [16q,16q+16) at spatial s = lane.
__global__ __launch_bounds__(256, 4)
void moe_kernel(const float* __restrict__ x,
                const float* __restrict__ dw_w,
                const float* __restrict__ dw_b,
                const float* __restrict__ ln_g,
                const float* __restrict__ ln_b,
                const float* __restrict__ pwin_w,
                const float* __restrict__ pwin_b,
                const float* __restrict__ pwout_w,
                const float* __restrict__ pwout_b,
                const int* __restrict__ sel_idx,
                const float* __restrict__ sel_w,
                float* __restrict__ out)
{
    __shared__ float xin[4096];
    __shared__ float ybuf[4096];

    int bid = blockIdx.x;
    int n = bid >> 3;             // patch
    int l = bid & 7;              // time step
    int b = n / (NPH*NPW);
    int rem = n - b*(NPH*NPW);
    int ph = rem / NPW, pw = rem - ph*NPW;

    int t = threadIdx.x;
    int s = t & 63;               // spatial position (i0*8+j0)
    int i0 = s >> 3, j0 = s & 7;
    int cbase = __builtin_amdgcn_readfirstlane((t >> 6) * 16);  // wave-uniform SGPR

    // ---- load input patch (vectorized) ----
    size_t xbl = ((size_t)(b*CCH)*LL + l)*HWX + (size_t)(ph*PP)*WW + pw*PP;
    for (int idx4 = t; idx4 < 1024; idx4 += 256) {
        int c = idx4 >> 4, r = idx4 & 15, i = r >> 1, j = (r & 1)*4;
        float4 v = *(const float4*)(x + xbl + (size_t)c*CSTRIDE + i*WW + j);
        *(float4*)(xin + c*64 + i*8 + j) = v;
    }

    int e0 = __builtin_amdgcn_readfirstlane(sel_idx[n*2]);
    int e1 = __builtin_amdgcn_readfirstlane(sel_idx[n*2+1]);
    float w0 = sel_w[n*2],  w1 = sel_w[n*2+1];

    float out_acc[16];
    #pragma unroll
    for (int k = 0; k < 16; ++k) out_acc[k] = 0.f;

    #pragma unroll 1
    for (int pass = 0; pass < 2; ++pass) {
        int e   = pass ? e1 : e0;      // SGPR
        float we = pass ? w1 : w0;

        __syncthreads();   // pass0: xin ready; pass1: prev-pass ybuf reads done

        // ---- depthwise 7x7 (zero-padded within patch) + LayerNorm over spatial ----
        const float* dwr = dw_w + e*CCH*49;      // uniform base
        const float* dbb = dw_b + e*CCH;
        float lngv = ln_g[e*64 + s];
        float lnbv = ln_b[e*64 + s];

        #pragma unroll
        for (int k = 0; k < 16; ++k) {
            int c = cbase + k;
            const float* xr = xin + c*64;
            const float* wr = dwr + c*49;
            float acc = dbb[c];
            #pragma unroll
            for (int di = 0; di < 7; ++di) {
                float w7[7];
                #pragma unroll
                for (int dj = 0; dj < 7; ++dj) w7[dj] = wr[di*7 + dj];   // uniform -> s_load
                int i2 = i0 + di - 3;
                if ((unsigned)i2 < 8u) {
                    #pragma unroll
                    for (int dj = 0; dj < 7; ++dj) {
                        int j2 = j0 + dj - 3;
                        if ((unsigned)j2 < 8u) {
                            acc = fmaf(xr[i2*8 + j2], w7[dj], acc);
                        }
                    }
                }
            }
            // wave-wide LN reduction (64 lanes = all spatial of this channel)
            float ssum = acc, ssq = acc*acc;
            #pragma unroll
            for (int m = 1; m < 64; m <<= 1) {
                ssum += __shfl_xor(ssum, m);
                ssq  += __shfl_xor(ssq, m);
            }
            float mu  = ssum * (1.f/64.f);
            float var = ssq * (1.f/64.f) - mu*mu;
            float inv = rsqrtf(var + 1e-5f);
            ybuf[c*64 + s] = (acc - mu) * inv * lngv + lnbv;
        }
        __syncthreads();

        // ---- pointwise in: C -> 2C, weights via scalar loads ----
        const float* wiA = pwin_w + e*8192 + cbase*64;
        const float* wiG = pwin_w + e*8192 + 4096 + cbase*64;
        float ha[16], hg[16];
        #pragma unroll
        for (int k = 0; k < 16; ++k) {
            ha[k] = pwin_b[e*128 + cbase + k];
            hg[k] = pwin_b[e*128 + 64 + cbase + k];
        }
        #pragma unroll
        for (int c8 = 0; c8 < 8; ++c8) {
            float y8[8];
            #pragma unroll
            for (int j = 0; j < 8; ++j) y8[j] = ybuf[(c8*8 + j)*64 + s];
            #pragma unroll
            for (int k = 0; k < 16; ++k) {
                #pragma unroll
                for (int j = 0; j < 8; ++j) {
                    ha[k] = fmaf(y8[j], wiA[k*64 + c8*8 + j], ha[k]);
                    hg[k] = fmaf(y8[j], wiG[k*64 + c8*8 + j], hg[k]);
                }
            }
        }

        // ---- SiLU gate ----
        float gated[16];
        #pragma unroll
        for (int k = 0; k < 16; ++k) {
            float a = ha[k];
            float sg = 1.f / (1.f + __expf(-a));
            gated[k] = a * sg * hg[k];
        }
        __syncthreads();   // all y reads done -> safe to overwrite ybuf
        #pragma unroll
        for (int k = 0; k < 16; ++k) ybuf[(cbase + k)*64 + s] = gated[k];
        __syncthreads();

        // ---- pointwise out + residual + combine ----
        const float* wo = pwout_w + e*4096 + cbase*64;
        float oacc[16];
        #pragma unroll
        for (int k = 0; k < 16; ++k) oacc[k] = pwout_b[e*64 + cbase + k];
        #pragma unroll
        for (int c8 = 0; c8 < 8; ++c8) {
            float g8[8];
            #pragma unroll
            for (int j = 0; j < 8; ++j) g8[j] = ybuf[(c8*8 + j)*64 + s];
            #pragma unroll
            for (int k = 0; k < 16; ++k) {
                #pragma unroll
                for (int j = 0; j < 8; ++j) {
                    oacc[k] = fmaf(g8[j], wo[k*64 + c8*8 + j], oacc[k]);
                }
            }
        }
        #pragma unroll
        for (int k = 0; k < 16; ++k) {
            out_acc[k] = fmaf(we, xin[(cbase + k)*64 + s] + oacc[k], out_acc[k]);
        }
    }

    // ---- write output ----
    size_t obl = ((size_t)(b*CCH)*LL + l)*HWX + (size_t)(ph*PP + i0)*WW + pw*PP + j0;
    #pragma unroll
    for (int k = 0; k < 16; ++k) {
        out[obl + (size_t)(cbase + k)*CSTRIDE] = out_acc[k];
    }
}

extern "C" void kernel_launch(void* const* d_in, const int* in_sizes, int n_in,
                              void* d_out, int out_size, void* d_ws, size_t ws_size,
                              hipStream_t stream) {
    const float* x        = (const float*)d_in[0];
    const float* router_w = (const float*)d_in[1];
    const float* router_b = (const float*)d_in[2];
    const float* dw_w     = (const float*)d_in[3];
    const float* dw_b     = (const float*)d_in[4];
    const float* ln_g     = (const float*)d_in[5];
    const float* ln_b     = (const float*)d_in[6];
    const float* pwin_w   = (const float*)d_in[7];
    const float* pwin_b   = (const float*)d_in[8];
    const float* pwout_w  = (const float*)d_in[9];
    const float* pwout_b  = (const float*)d_in[10];
    float* out = (float*)d_out;

    int*   sel_idx = (int*)d_ws;
    float* sel_w   = (float*)((char*)d_ws + NPAT*2*sizeof(int));

    router_kernel<<<NPAT, 256, 0, stream>>>(x, router_w, router_b, sel_idx, sel_w);
    moe_kernel<<<NPAT*LL, 256, 0, stream>>>(x, dw_w, dw_b, ln_g, ln_b,
                                            pwin_w, pwin_b, pwout_w, pwout_b,
                                            sel_idx, sel_w, out);
}

// Round 3
// 370.971 us; speedup vs baseline: 16.1062x; 13.4617x over previous
//
#include <hip/hip_runtime.h>

#define NB 2
#define CCH 64
#define LL 8
#define HH 160
#define WW 160
#define PP 8
#define NPH 20
#define NPW 20
#define NPAT (NB*NPH*NPW)      // 800
#define NE 8
#define HWX (HH*WW)            // 25600
#define CSTRIDE (LL*HWX)       // 204800

typedef float f32x16 __attribute__((ext_vector_type(16)));
typedef short bf16x8 __attribute__((ext_vector_type(8)));

__device__ __host__ __forceinline__ unsigned short f2bf(float f) {
    unsigned u = __builtin_bit_cast(unsigned, f);
    u = (u + 0x7FFFu + ((u >> 16) & 1u)) >> 16;
    return (unsigned short)u;
}

template<int CTRL>
__device__ __forceinline__ float dpp0(float v) {   // old=0, bound_ctrl=true
    return __builtin_bit_cast(float, __builtin_amdgcn_update_dpp(
        0, __builtin_bit_cast(int, v), CTRL, 0xF, 0xF, true));
}
__device__ __forceinline__ float dpp_xor1(float v) {  // quad_perm [1,0,3,2]
    int s = __builtin_bit_cast(int, v);
    return __builtin_bit_cast(float, __builtin_amdgcn_update_dpp(s, s, 0xB1, 0xF, 0xF, false));
}
__device__ __forceinline__ float wsum64(float v) {
    v += dpp0<0x111>(v);   // row_shr:1
    v += dpp0<0x112>(v);   // row_shr:2
    v += dpp0<0x114>(v);   // row_shr:4
    v += dpp0<0x118>(v);   // row_shr:8
    v += dpp0<0x142>(v);   // row_bcast15
    v += dpp0<0x143>(v);   // row_bcast31
    return __builtin_bit_cast(float, __builtin_amdgcn_readlane(__builtin_bit_cast(int, v), 63));
}
__device__ __forceinline__ float bperm(int a4, float v) {
    return __builtin_bit_cast(float, __builtin_amdgcn_ds_bpermute(a4, __builtin_bit_cast(int, v)));
}

// ---------------- Weight prep: bf16 cast (+ a/g row interleave for pwin) ----------------
__global__ __launch_bounds__(256)
void prep_kernel(const float* __restrict__ pwin_w, const float* __restrict__ pwout_w,
                 unsigned short* __restrict__ w1t, unsigned short* __restrict__ w2t)
{
    int idx = blockIdx.x * 256 + threadIdx.x;
    if (idx < NE*128*64) {
        int e = idx >> 13, r = (idx >> 6) & 127, c = idx & 63;
        int orig = (r & 1) ? 64 + (r >> 1) : (r >> 1);
        w1t[idx] = f2bf(pwin_w[(e << 13) + orig*64 + c]);
    }
    if (idx < NE*64*64) {
        w2t[idx] = f2bf(pwout_w[idx]);
    }
}

// ---------------- Router ----------------
__global__ __launch_bounds__(256)
void router_kernel(const float* __restrict__ x,
                   const float* __restrict__ rw,
                   const float* __restrict__ rb,
                   int* __restrict__ sel_idx,
                   float* __restrict__ sel_w)
{
    int n = blockIdx.x;
    int b = n / (NPH*NPW);
    int rem = n - b*(NPH*NPW);
    int ph = rem / NPW, pw = rem - ph*NPW;
    int t = threadIdx.x;
    int c = t >> 2, part = t & 3;

    const float* xl0 = x + ((size_t)(b*CCH + c)*LL)*HWX + (size_t)(ph*PP)*WW + pw*PP;
    float s = 0.f;
    for (int l = part*2; l < part*2 + 2; ++l) {
        const float* xl = xl0 + (size_t)l*HWX;
        #pragma unroll
        for (int i = 0; i < 8; ++i) {
            float4 v0 = *(const float4*)(xl + i*WW);
            float4 v1 = *(const float4*)(xl + i*WW + 4);
            s += v0.x+v0.y+v0.z+v0.w + v1.x+v1.y+v1.z+v1.w;
        }
    }
    s += __shfl_xor(s, 1);
    s += __shfl_xor(s, 2);

    __shared__ float meanc[CCH];
    __shared__ float logits[NE];
    if (part == 0) meanc[c] = s * (1.f/512.f);
    __syncthreads();
    if (t < NE) {
        float acc = rb[t];
        for (int cc = 0; cc < CCH; ++cc) acc += meanc[cc] * rw[t*CCH + cc];
        logits[t] = acc;
    }
    __syncthreads();
    if (t == 0) {
        float m0 = -1e30f; int i0 = 0;
        #pragma unroll
        for (int e = 0; e < NE; ++e) { float v = logits[e]; if (v > m0) { m0 = v; i0 = e; } }
        float m1 = -1e30f; int i1 = 0;
        #pragma unroll
        for (int e = 0; e < NE; ++e) { if (e != i0) { float v = logits[e]; if (v > m1) { m1 = v; i1 = e; } } }
        float dd = __expf(m1 - m0);
        float inv = 1.f / (1.f + dd);
        sel_idx[n*2]   = i0;  sel_idx[n*2+1] = i1;
        sel_w[n*2]     = inv; sel_w[n*2+1]   = dd * inv;
    }
}

// ---------------- Main MoE kernel ----------------
// LDS 32 KiB: xin fp32[64c][64s] | {Y bf16[64s][64k] swz, G bf16[64s][64k] swz} aliased by obuf fp32
__global__ __launch_bounds__(256, 4)
void moe_kernel(const float* __restrict__ x,
                const float* __restrict__ dw_w,
                const float* __restrict__ dw_b,
                const float* __restrict__ ln_g,
                const float* __restrict__ ln_b,
                const float* __restrict__ pwin_b,
                const float* __restrict__ pwout_b,
                const unsigned short* __restrict__ w1t,
                const unsigned short* __restrict__ w2t,
                const int* __restrict__ sel_idx,
                const float* __restrict__ sel_w,
                float* __restrict__ out)
{
    __shared__ __align__(16) unsigned smem[8192];
    float* xin   = (float*)smem;          // dwords [0, 4096)
    unsigned* Y  = smem + 4096;           // dwords [4096, 6144)
    unsigned* G  = smem + 6144;           // dwords [6144, 8192)
    float* obuf  = (float*)(smem + 4096); // aliases Y+G

    int bid = blockIdx.x;
    int n = bid >> 3;
    int l = bid & 7;
    int b = n / (NPH*NPW);
    int rem = n - b*(NPH*NPW);
    int ph = rem / NPW, pw = rem - ph*NPW;

    int t = threadIdx.x;
    int lane = t & 63;
    int q = __builtin_amdgcn_readfirstlane(t >> 6);
    int cbase = q * 16;
    int i0 = lane >> 3, j0 = lane & 7;
    int laneM = lane & 31, hi = lane >> 5;

    // masks & bpermute addresses (loop-invariant)
    bool l1ok = j0 < 7, l2ok = j0 < 6, l3ok = j0 < 5;
    bool r1ok = j0 > 0, r2ok = j0 > 1, r3ok = j0 > 2;
    bool u1ok = i0 < 7, u2ok = i0 < 6, u3ok = i0 < 5;
    bool d1ok = i0 > 0, d2ok = i0 > 1, d3ok = i0 > 2;
    int aup1 = ((lane + 8)  & 63) << 2, aup2 = ((lane + 16) & 63) << 2, aup3 = ((lane + 24) & 63) << 2;
    int adn1 = ((lane - 8)  & 63) << 2, adn2 = ((lane - 16) & 63) << 2, adn3 = ((lane - 24) & 63) << 2;

    // ---- stage input patch ----
    size_t pbase = ((size_t)(b*CCH)*LL + l)*HWX + (size_t)(ph*PP)*WW + pw*PP;
    for (int idx4 = t; idx4 < 1024; idx4 += 256) {
        int c = idx4 >> 4, r = idx4 & 15, ii = r >> 1, jj = (r & 1)*4;
        float4 v = *(const float4*)(x + pbase + (size_t)c*CSTRIDE + ii*WW + jj);
        *(float4*)(xin + c*64 + ii*8 + jj) = v;
    }

    int e0 = __builtin_amdgcn_readfirstlane(sel_idx[n*2]);
    int e1 = __builtin_amdgcn_readfirstlane(sel_idx[n*2+1]);
    float w0 = sel_w[n*2], w1 = sel_w[n*2+1];

    f32x16 out_acc;
    #pragma unroll
    for (int i = 0; i < 16; ++i) out_acc[i] = 0.f;

    int dprime = 32*q + laneM;                 // GEMM1 output column (interleaved a/g)
    int borig  = (dprime & 1) ? 64 + (dprime >> 1) : (dprime >> 1);
    int cn     = 32*(q >> 1) + laneM;          // GEMM2 output channel
    int xv     = (lane & 7) << 2;              // Y-write swizzle (s = lane)
    bool oddl  = (lane & 1) != 0;
    int kg     = 16*q + (laneM >> 1);          // gated-channel index this lane writes
    int kdg    = kg >> 1, kbit = kg & 1;
    int srow_b = (oddl ? 32 : 0) + 4*hi;

    #pragma unroll 1
    for (int pass = 0; pass < 2; ++pass) {
        int e = pass ? e1 : e0;
        float we = pass ? w1 : w0;

        // prefetch B fragments (L2-hot) + per-pass params
        const unsigned short* w1e = w1t + ((size_t)e << 13);
        const unsigned short* w2e = w2t + ((size_t)e << 12);
        uint4 b1f[4], b2f[4];
        #pragma unroll
        for (int ks = 0; ks < 4; ++ks)
            b1f[ks] = *(const uint4*)(w1e + (32*q + laneM)*64 + 16*ks + 8*hi);
        #pragma unroll
        for (int ks = 0; ks < 4; ++ks)
            b2f[ks] = *(const uint4*)(w2e + cn*64 + 16*ks + 8*hi);
        float bias1 = pwin_b[e*128 + borig];
        float bias2 = pwout_b[e*64 + cn];
        float lng = ln_g[e*64 + lane];
        float lnb = ln_b[e*64 + lane];

        __syncthreads();   // xin ready (pass0) / prev-pass GEMM2 G-reads done (pass1)

        // ---- depthwise 7x7 + LayerNorm, 16 channels per wave ----
        unsigned ypack[8];
        #pragma unroll
        for (int i = 0; i < 8; ++i) ypack[i] = 0u;

        #pragma unroll
        for (int m = 0; m < 16; ++m) {
            int c = cbase + m;
            const float* wr = dw_w + ((size_t)e*CCH + c)*49;
            float v = xin[c*64 + lane];
            float xl1 = dpp0<0x101>(v); xl1 = l1ok ? xl1 : 0.f;
            float xl2 = dpp0<0x102>(v); xl2 = l2ok ? xl2 : 0.f;
            float xl3 = dpp0<0x103>(v); xl3 = l3ok ? xl3 : 0.f;
            float xr1 = dpp0<0x111>(v); xr1 = r1ok ? xr1 : 0.f;
            float xr2 = dpp0<0x112>(v); xr2 = r2ok ? xr2 : 0.f;
            float xr3 = dpp0<0x113>(v); xr3 = r3ok ? xr3 : 0.f;
            float S0,S1,S2,S3,S4,S5,S6;
            #define ROW1D(SS, di) { const float* w7 = wr + (di)*7;            \
                float a = xr3 * w7[0];  a = fmaf(xr2, w7[1], a);              \
                a = fmaf(xr1, w7[2], a); a = fmaf(v,  w7[3], a);              \
                a = fmaf(xl1, w7[4], a); a = fmaf(xl2, w7[5], a);             \
                a = fmaf(xl3, w7[6], a); SS = a; }
            ROW1D(S0,0) ROW1D(S1,1) ROW1D(S2,2) ROW1D(S3,3) ROW1D(S4,4) ROW1D(S5,5) ROW1D(S6,6)
            #undef ROW1D
            float o = S3 + dw_b[(size_t)e*CCH + c];
            float p;
            p = bperm(aup1, S4); o += u1ok ? p : 0.f;
            p = bperm(aup2, S5); o += u2ok ? p : 0.f;
            p = bperm(aup3, S6); o += u3ok ? p : 0.f;
            p = bperm(adn1, S2); o += d1ok ? p : 0.f;
            p = bperm(adn2, S1); o += d2ok ? p : 0.f;
            p = bperm(adn3, S0); o += d3ok ? p : 0.f;
            float ssum = wsum64(o);
            float ssq  = wsum64(o*o);
            float mu  = ssum * 0.015625f;
            float var = ssq  * 0.015625f - mu*mu;
            float yv  = (o - mu) * rsqrtf(var + 1e-5f) * lng + lnb;
            ypack[m >> 1] |= ((unsigned)f2bf(yv)) << ((m & 1) * 16);
        }
        {   // Y[s=lane][k], swizzled dword: s*32 + (kd ^ ((s&7)<<2))
            uint4 v0; v0.x = ypack[0]; v0.y = ypack[1]; v0.z = ypack[2]; v0.w = ypack[3];
            uint4 v1; v1.x = ypack[4]; v1.y = ypack[5]; v1.z = ypack[6]; v1.w = ypack[7];
            *(uint4*)&Y[lane*32 + ((8*q + 0) ^ xv)] = v0;
            *(uint4*)&Y[lane*32 + ((8*q + 4) ^ xv)] = v1;
        }
        __syncthreads();

        // ---- GEMM1: h[64s][128d'] = Y * W1t^T, wave q owns d' in [32q, 32q+32) ----
        f32x16 acc0, acc1;
        #pragma unroll
        for (int i = 0; i < 16; ++i) { acc0[i] = 0.f; acc1[i] = 0.f; }
        #pragma unroll
        for (int ks = 0; ks < 4; ++ks) {
            int kd = 8*ks + 4*hi;
            int s0 = laneM, s1 = 32 + laneM;
            uint4 a0 = *(const uint4*)&Y[s0*32 + (kd ^ ((s0 & 7) << 2))];
            uint4 a1 = *(const uint4*)&Y[s1*32 + (kd ^ ((s1 & 7) << 2))];
            bf16x8 bv = __builtin_bit_cast(bf16x8, b1f[ks]);
            acc0 = __builtin_amdgcn_mfma_f32_32x32x16_bf16(__builtin_bit_cast(bf16x8, a0), bv, acc0, 0, 0, 0);
            acc1 = __builtin_amdgcn_mfma_f32_32x32x16_bf16(__builtin_bit_cast(bf16x8, a1), bv, acc1, 0, 0, 0);
        }
        // ---- gate: silu(a)*g, write G bf16 (even lanes->Mtile0 row, odd->Mtile1) ----
        #pragma unroll
        for (int r = 0; r < 16; ++r) {
            float h0 = acc0[r] + bias1;
            float h1 = acc1[r] + bias1;
            float p0 = dpp_xor1(h0);
            float p1 = dpp_xor1(h1);
            float a0 = oddl ? p0 : h0, g0 = oddl ? h0 : p0;
            float a1 = oddl ? p1 : h1, g1 = oddl ? h1 : p1;
            float ga = __fdividef(a0, 1.f + __expf(-a0)) * g0;
            float gb = __fdividef(a1, 1.f + __expf(-a1)) * g1;
            float val = oddl ? gb : ga;
            int srow = srow_b + (r & 3) + 8*(r >> 2);
            int gd = srow*32 + (kdg ^ ((srow & 7) << 2));
            ((unsigned short*)G)[gd*2 + kbit] = f2bf(val);
        }
        __syncthreads();

        // ---- GEMM2: o[64s][64c] = G * W2t^T, wave q: Mtile q&1, Ntile q>>1 ----
        f32x16 gacc;
        #pragma unroll
        for (int i = 0; i < 16; ++i) gacc[i] = 0.f;
        #pragma unroll
        for (int ks = 0; ks < 4; ++ks) {
            int s = 32*(q & 1) + laneM;
            int kd = 8*ks + 4*hi;
            uint4 ag = *(const uint4*)&G[s*32 + (kd ^ ((s & 7) << 2))];
            gacc = __builtin_amdgcn_mfma_f32_32x32x16_bf16(
                __builtin_bit_cast(bf16x8, ag), __builtin_bit_cast(bf16x8, b2f[ks]), gacc, 0, 0, 0);
        }
        #pragma unroll
        for (int r = 0; r < 16; ++r) out_acc[r] += we * (gacc[r] + bias2);
    }

    // ---- transpose through obuf (aliases Y/G) and write out coalesced ----
    __syncthreads();
    {
        int s_base = 32*(q & 1) + 4*hi;
        #pragma unroll
        for (int r = 0; r < 16; ++r) {
            int s = s_base + (r & 3) + 8*(r >> 2);
            obuf[cn*64 + (s ^ (cn & 31))] = out_acc[r];
        }
    }
    __syncthreads();
    #pragma unroll
    for (int m = 0; m < 16; ++m) {
        int c = cbase + m;
        float val = obuf[c*64 + (lane ^ (c & 31))] + xin[c*64 + lane];
        out[pbase + (size_t)c*CSTRIDE + i0*WW + j0] = val;
    }
}

extern "C" void kernel_launch(void* const* d_in, const int* in_sizes, int n_in,
                              void* d_out, int out_size, void* d_ws, size_t ws_size,
                              hipStream_t stream) {
    const float* x        = (const float*)d_in[0];
    const float* router_w = (const float*)d_in[1];
    const float* router_b = (const float*)d_in[2];
    const float* dw_w     = (const float*)d_in[3];
    const float* dw_b     = (const float*)d_in[4];
    const float* ln_g     = (const float*)d_in[5];
    const float* ln_b     = (const float*)d_in[6];
    const float* pwin_w   = (const float*)d_in[7];
    const float* pwin_b   = (const float*)d_in[8];
    const float* pwout_w  = (const float*)d_in[9];
    const float* pwout_b  = (const float*)d_in[10];
    float* out = (float*)d_out;

    char* ws = (char*)d_ws;
    int*            sel_idx = (int*)ws;                      // 6400 B
    float*          sel_w   = (float*)(ws + 6400);           // 6400 B
    unsigned short* w1t     = (unsigned short*)(ws + 12800); // 131072 B
    unsigned short* w2t     = (unsigned short*)(ws + 143872);// 65536 B

    prep_kernel<<<256, 256, 0, stream>>>(pwin_w, pwout_w, w1t, w2t);
    router_kernel<<<NPAT, 256, 0, stream>>>(x, router_w, router_b, sel_idx, sel_w);
    moe_kernel<<<NPAT*LL, 256, 0, stream>>>(x, dw_w, dw_b, ln_g, ln_b,
                                            pwin_b, pwout_b, w1t, w2t,
                                            sel_idx, sel_w, out);
}